// Round 15
// baseline (186.945 us; speedup 1.0000x reference)
//
#include <hip/hip_runtime.h>
#include <hip/hip_fp16.h>
#include <math.h>

#define N_NODES 50000
#define N_EDGES 1000000
#define F_IN 128
#define HID 16
#define N_CLS 40
#define HEADS 8
#define ET (N_EDGES + N_NODES)
#define XB ((N_NODES + 63) / 64)      // 782 xform blocks
#define HB ((ET + 255) / 256)         // 4103 hist blocks
#define NSCB ((N_NODES + 255) / 256)  // 196 scan blocks

typedef __attribute__((ext_vector_type(8))) _Float16 f16x8;
typedef __attribute__((ext_vector_type(4))) float f32x4;

// monotone float<->uint encoding for atomicMax on floats
__device__ __forceinline__ unsigned encf(float f) {
  unsigned b = __float_as_uint(f);
  return (b & 0x80000000u) ? ~b : (b | 0x80000000u);
}
__device__ __forceinline__ float decf(unsigned k) {
  unsigned b = (k & 0x80000000u) ? (k ^ 0x80000000u) : ~k;
  return __uint_as_float(b);
}

// ---------------- conv1 transform: f16 MFMA GEMM (+ hist blocks, as1-max) ----
// Tile 64 nodes x 128 ch; wave = 16 nodes. x, W^T staged f16 in LDS with
// XOR swizzle (byte ^= (row&7)<<4) -> 2-way conflicts (free).
// A-frag: lane holds x[node=lane&15][k=(lane>>4)*8+j]; B-frag: W^T[ch][k] same.
// C/D (HW-verified): ch = frag*16 + (lane&15), node = n0 + (lane>>4)*4 + reg.

__global__ __launch_bounds__(256) void k_xform1(
    const float* __restrict__ x, const float* __restrict__ W1,
    const float* __restrict__ att_s, const float* __restrict__ att_d,
    const int* __restrict__ ei, int* __restrict__ deg, int* __restrict__ epos,
    __half* __restrict__ h1, float* __restrict__ as1, float* __restrict__ ad1,
    unsigned* __restrict__ enc1) {
  if (blockIdx.x >= XB) {  // histogram blocks
    int i = (blockIdx.x - XB) * 256 + threadIdx.x;
    if (i < ET) {
      int dd = (i < N_EDGES) ? ei[N_EDGES + i] : (i - N_EDGES);
      epos[i] = atomicAdd(&deg[dd], 1);
    }
    return;
  }
  __shared__ __half xl[64 * 128];    // 16KB, swizzled
  __shared__ __half wt[128 * 128];   // 32KB, transposed W, swizzled
  __shared__ unsigned encl[8];
  int t = threadIdx.x;
  if (t < 8) encl[t] = 0u;
  int base = blockIdx.x * 64;
  const float4* x4 = (const float4*)x;
  const float4* W4 = (const float4*)W1;

  // stage x: f32 -> f16, swizzled rows (256B/node)
#pragma unroll
  for (int u = 0; u < 8; u++) {
    int i = t + u * 256;
    int n = i >> 5, q = i & 31;
    int gn = base + n;
    float4 v = {0.f, 0.f, 0.f, 0.f};
    if (gn < N_NODES) v = x4[(size_t)gn * 32 + q];
    uint2 pk;
    __half2* ph = (__half2*)&pk;
    ph[0] = __floats2half2_rn(v.x, v.y);
    ph[1] = __floats2half2_rn(v.z, v.w);
    unsigned byte = (unsigned)(n * 256 + q * 8) ^ ((n & 7) << 4);
    *(uint2*)((char*)xl + byte) = pk;
  }
  // stage W transposed: 4k x 4c subtiles, f32 -> f16, swizzled
#pragma unroll
  for (int u = 0; u < 4; u++) {
    int i = t + u * 256;
    int kt = i >> 5, ct = i & 31;
    int k0 = kt * 4;
    float4 r0 = W4[(size_t)(k0 + 0) * 32 + ct];
    float4 r1 = W4[(size_t)(k0 + 1) * 32 + ct];
    float4 r2 = W4[(size_t)(k0 + 2) * 32 + ct];
    float4 r3 = W4[(size_t)(k0 + 3) * 32 + ct];
    int chb = ct * 4;
    uint2 pk;
    __half2* ph = (__half2*)&pk;
    ph[0] = __floats2half2_rn(r0.x, r1.x); ph[1] = __floats2half2_rn(r2.x, r3.x);
    *(uint2*)((char*)wt + (((unsigned)((chb + 0) * 256 + k0 * 2)) ^ (((chb + 0) & 7) << 4))) = pk;
    ph[0] = __floats2half2_rn(r0.y, r1.y); ph[1] = __floats2half2_rn(r2.y, r3.y);
    *(uint2*)((char*)wt + (((unsigned)((chb + 1) * 256 + k0 * 2)) ^ (((chb + 1) & 7) << 4))) = pk;
    ph[0] = __floats2half2_rn(r0.z, r1.z); ph[1] = __floats2half2_rn(r2.z, r3.z);
    *(uint2*)((char*)wt + (((unsigned)((chb + 2) * 256 + k0 * 2)) ^ (((chb + 2) & 7) << 4))) = pk;
    ph[0] = __floats2half2_rn(r0.w, r1.w); ph[1] = __floats2half2_rn(r2.w, r3.w);
    *(uint2*)((char*)wt + (((unsigned)((chb + 3) * 256 + k0 * 2)) ^ (((chb + 3) & 7) << 4))) = pk;
  }
  __syncthreads();

  int l = t & 63, wv = t >> 6;
  int lm = l & 15, lh = l >> 4;
  int n0 = wv * 16;
  int node = n0 + lm;
  bool wvalid = (base + n0) < N_NODES;  // 50000 % 16 == 0: all-or-nothing per wave

  f32x4 acc[8];
#pragma unroll
  for (int f = 0; f < 8; f++) acc[f] = (f32x4){0.f, 0.f, 0.f, 0.f};

#pragma unroll
  for (int kb = 0; kb < 4; kb++) {
    int kbase = kb * 32 + lh * 8;
    unsigned ab = ((unsigned)(node * 256 + kbase * 2)) ^ ((node & 7) << 4);
    f16x8 af = *(const f16x8*)((const char*)xl + ab);
#pragma unroll
    for (int f = 0; f < 8; f++) {
      int ch = f * 16 + lm;
      unsigned bb = ((unsigned)(ch * 256 + kbase * 2)) ^ ((ch & 7) << 4);
      f16x8 bf = *(const f16x8*)((const char*)wt + bb);
      acc[f] = __builtin_amdgcn_mfma_f32_16x16x32_f16(af, bf, acc[f], 0, 0, 0);
    }
  }

  // epilogue: per-head att dots (head == frag since HID=16), h1 f16 store
  int nr = base + n0 + lh * 4;  // node of reg 0 for this lane
#pragma unroll
  for (int f = 0; f < 8; f++) {
    float asv = att_s[f * 16 + lm];
    float adv = att_d[f * 16 + lm];
    float ps0 = acc[f].x * asv, ps1 = acc[f].y * asv;
    float ps2 = acc[f].z * asv, ps3 = acc[f].w * asv;
    float pd0 = acc[f].x * adv, pd1 = acc[f].y * adv;
    float pd2 = acc[f].z * adv, pd3 = acc[f].w * adv;
#pragma unroll
    for (int off = 1; off <= 8; off <<= 1) {
      ps0 += __shfl_xor(ps0, off); ps1 += __shfl_xor(ps1, off);
      ps2 += __shfl_xor(ps2, off); ps3 += __shfl_xor(ps3, off);
      pd0 += __shfl_xor(pd0, off); pd1 += __shfl_xor(pd1, off);
      pd2 += __shfl_xor(pd2, off); pd3 += __shfl_xor(pd3, off);
    }
    if (wvalid) {
      if (lm == 0) {
        as1[(nr + 0) * 8 + f] = ps0; ad1[(nr + 0) * 8 + f] = pd0;
        as1[(nr + 1) * 8 + f] = ps1; ad1[(nr + 1) * 8 + f] = pd1;
        as1[(nr + 2) * 8 + f] = ps2; ad1[(nr + 2) * 8 + f] = pd2;
        as1[(nr + 3) * 8 + f] = ps3; ad1[(nr + 3) * 8 + f] = pd3;
        float m = fmaxf(fmaxf(ps0, ps1), fmaxf(ps2, ps3));
        atomicMax(&encl[f], encf(m));
      }
      int cb = f * 16 + lm;
      h1[(size_t)(nr + 0) * 128 + cb] = __float2half(acc[f].x);
      h1[(size_t)(nr + 1) * 128 + cb] = __float2half(acc[f].y);
      h1[(size_t)(nr + 2) * 128 + cb] = __float2half(acc[f].z);
      h1[(size_t)(nr + 3) * 128 + cb] = __float2half(acc[f].w);
    }
  }
  __syncthreads();
  if (t < 8) atomicMax(&enc1[t], encl[t]);
}

// ---------------- 3-kernel coalesced exclusive scan of deg -> start ----------

__global__ __launch_bounds__(256) void k_scanA(const int* __restrict__ deg,
                                               int* __restrict__ bsum) {
  int i = blockIdx.x * 256 + threadIdx.x;
  int v = (i < N_NODES) ? deg[i] : 0;
#pragma unroll
  for (int off = 32; off; off >>= 1) v += __shfl_xor(v, off);
  __shared__ int ws[4];
  if ((threadIdx.x & 63) == 0) ws[threadIdx.x >> 6] = v;
  __syncthreads();
  if (threadIdx.x == 0) bsum[blockIdx.x] = ws[0] + ws[1] + ws[2] + ws[3];
}

__global__ __launch_bounds__(256) void k_scanB(const int* __restrict__ bsum,
                                               int* __restrict__ boff,
                                               int* __restrict__ start,
                                               const unsigned* __restrict__ enc1,
                                               float* __restrict__ fmax1) {
  __shared__ int s[256];
  int t = threadIdx.x;
  int v0 = (t < NSCB) ? bsum[t] : 0;
  s[t] = v0;
  __syncthreads();
  for (int off = 1; off < 256; off <<= 1) {
    int v = (t >= off) ? s[t - off] : 0;
    __syncthreads();
    s[t] += v;
    __syncthreads();
  }
  boff[t] = s[t] - v0;  // exclusive
  if (t == 0) start[N_NODES] = ET;
  if (t < 8) fmax1[t] = decf(enc1[t]);  // pre-decode as1 per-head max
}

__global__ __launch_bounds__(256) void k_scanC(const int* __restrict__ deg,
                                               const int* __restrict__ boff,
                                               int* __restrict__ start) {
  __shared__ int s[256];
  int t = threadIdx.x;
  int i = blockIdx.x * 256 + t;
  int v0 = (i < N_NODES) ? deg[i] : 0;
  s[t] = v0;
  __syncthreads();
  for (int off = 1; off < 256; off <<= 1) {
    int v = (t >= off) ? s[t - off] : 0;
    __syncthreads();
    s[t] += v;
    __syncthreads();
  }
  if (i < N_NODES) start[i] = boff[blockIdx.x] + s[t] - v0;
}

// atomic-free scatter: position precomputed by hist
__global__ void k_scatter(const int* __restrict__ ei, const int* __restrict__ start,
                          const int* __restrict__ epos, int* __restrict__ esrc) {
  int i = blockIdx.x * blockDim.x + threadIdx.x;
  if (i >= ET) return;
  int s, d;
  if (i < N_EDGES) { s = ei[i]; d = ei[N_EDGES + i]; }
  else { s = i - N_EDGES; d = s; }
  esrc[start[d] + epos[i]] = s;
}

// ---------------- conv1 aggregation + fused conv2 transform ----------------
// 16-lane groups: wave = 4 dst; lane = 8 channels (16B dwordx4 gathers).
// 8-deep gather unroll; de-aligned p_t group stride (656B) to stagger banks.

__global__ __launch_bounds__(256) void k_agg1(
    const __half* __restrict__ h1, const float* __restrict__ as1,
    const float* __restrict__ ad1, const int* __restrict__ start,
    const int* __restrict__ esrc, const float* __restrict__ b1,
    const float* __restrict__ W2, const float* __restrict__ att_s2,
    const float* __restrict__ att_d2, const float* __restrict__ fmax1,
    __half* __restrict__ h2, float* __restrict__ as2, float* __restrict__ ad2) {
  __shared__ __align__(16) __half2 p_t[4][4 * 164];  // [wave][g*164 + head*20 + e]
  __shared__ __align__(16) int s_off[4][4][20];      // [wave][g][16e+pad]
  __shared__ float w2s[16 * 40];
  int t = threadIdx.x;
  for (int i = t; i < 640; i += 256) w2s[i] = W2[i];
  __syncthreads();

  int wave = t >> 6, lane = t & 63;
  int g = lane >> 4, li = lane & 15;
  int d = blockIdx.x * 16 + wave * 4 + g;  // 3125*16 = 50000 exact
  int s0 = start[d];
  int deg = start[d + 1] - s0;

  int dm = deg;
  dm = max(dm, __shfl_xor(dm, 16));
  dm = max(dm, __shfl_xor(dm, 32));

  float4 av0 = *(const float4*)(ad1 + d * 8);
  float4 av1 = *(const float4*)(ad1 + d * 8 + 4);
  float ad_[8] = {av0.x, av0.y, av0.z, av0.w, av1.x, av1.y, av1.z, av1.w};
  float c_[8];
#pragma unroll
  for (int h = 0; h < 8; h++) {
    float e = fmax1[h] + ad_[h];
    c_[h] = e > 0.f ? e : 0.2f * e;
  }

  float den = 0.f;
  float accf[8];
#pragma unroll
  for (int k = 0; k < 8; k++) accf[k] = 0.f;

  int hsel = li >> 1;
  const char* h1l = (const char*)(h1 + li * 8);  // lane's 16B channel chunk
  __half2* ptw = &p_t[wave][g * 164];
  const int* so = &s_off[wave][g][0];

  for (int be = 0; be < dm; be += 16) {
    int cnt = deg - be;  // may be <= 0
    bool act = li < cnt;
    int s = 0;
    if (act) s = esrc[s0 + be + li];
    s_off[wave][g][li] = act ? (s << 8) : 0;
    float4 p0 = {0.f, 0.f, 0.f, 0.f}, p1 = {0.f, 0.f, 0.f, 0.f};
    if (act) {
      p0 = *(const float4*)(as1 + (size_t)s * 8);
      p1 = *(const float4*)(as1 + (size_t)s * 8 + 4);
    }
    float ev[8] = {p0.x, p0.y, p0.z, p0.w, p1.x, p1.y, p1.z, p1.w};
#pragma unroll
    for (int h = 0; h < 8; h++) {
      float v = ev[h] + ad_[h];
      v = v > 0.f ? v : 0.2f * v;
      float pv = act ? __expf(v - c_[h]) : 0.f;
      __half hp = __float2half(pv);
      ptw[h * 20 + li] = __half2{hp, hp};
    }
    asm volatile("s_waitcnt lgkmcnt(0)" ::: "memory");

    int cm = min(dm - be, 16);
    const __half2* pt = ptw + hsel * 20;
    __half2 a0 = __floats2half2_rn(0.f, 0.f);
    __half2 a1 = __floats2half2_rn(0.f, 0.f);
    __half2 a2 = __floats2half2_rn(0.f, 0.f);
    __half2 a3 = __floats2half2_rn(0.f, 0.f);
    for (int e = 0; e < cm; e += 8) {  // pad entries are (p=0, off=0): safe
      int4 s4 = *(const int4*)&so[e];
      int4 s8 = *(const int4*)&so[e + 4];
      uint4 pwA = *(const uint4*)&pt[e];
      uint4 pwB = *(const uint4*)&pt[e + 4];
      const __half2* ppA = (const __half2*)&pwA;
      const __half2* ppB = (const __half2*)&pwB;
      uint4 hA = *(const uint4*)(h1l + (unsigned)s4.x);
      uint4 hB = *(const uint4*)(h1l + (unsigned)s4.y);
      uint4 hC = *(const uint4*)(h1l + (unsigned)s4.z);
      uint4 hD = *(const uint4*)(h1l + (unsigned)s4.w);
      uint4 hE = *(const uint4*)(h1l + (unsigned)s8.x);
      uint4 hF = *(const uint4*)(h1l + (unsigned)s8.y);
      uint4 hG = *(const uint4*)(h1l + (unsigned)s8.z);
      uint4 hH = *(const uint4*)(h1l + (unsigned)s8.w);
      const __half2* vA = (const __half2*)&hA;
      const __half2* vB = (const __half2*)&hB;
      const __half2* vC = (const __half2*)&hC;
      const __half2* vD = (const __half2*)&hD;
      const __half2* vE = (const __half2*)&hE;
      const __half2* vF = (const __half2*)&hF;
      const __half2* vG = (const __half2*)&hG;
      const __half2* vH = (const __half2*)&hH;
      a0 = __hfma2(vA[0], ppA[0], a0); a1 = __hfma2(vA[1], ppA[0], a1);
      a2 = __hfma2(vA[2], ppA[0], a2); a3 = __hfma2(vA[3], ppA[0], a3);
      a0 = __hfma2(vB[0], ppA[1], a0); a1 = __hfma2(vB[1], ppA[1], a1);
      a2 = __hfma2(vB[2], ppA[1], a2); a3 = __hfma2(vB[3], ppA[1], a3);
      a0 = __hfma2(vC[0], ppA[2], a0); a1 = __hfma2(vC[1], ppA[2], a1);
      a2 = __hfma2(vC[2], ppA[2], a2); a3 = __hfma2(vC[3], ppA[2], a3);
      a0 = __hfma2(vD[0], ppA[3], a0); a1 = __hfma2(vD[1], ppA[3], a1);
      a2 = __hfma2(vD[2], ppA[3], a2); a3 = __hfma2(vD[3], ppA[3], a3);
      a0 = __hfma2(vE[0], ppB[0], a0); a1 = __hfma2(vE[1], ppB[0], a1);
      a2 = __hfma2(vE[2], ppB[0], a2); a3 = __hfma2(vE[3], ppB[0], a3);
      a0 = __hfma2(vF[0], ppB[1], a0); a1 = __hfma2(vF[1], ppB[1], a1);
      a2 = __hfma2(vF[2], ppB[1], a2); a3 = __hfma2(vF[3], ppB[1], a3);
      a0 = __hfma2(vG[0], ppB[2], a0); a1 = __hfma2(vG[1], ppB[2], a1);
      a2 = __hfma2(vG[2], ppB[2], a2); a3 = __hfma2(vG[3], ppB[2], a3);
      a0 = __hfma2(vH[0], ppB[3], a0); a1 = __hfma2(vH[1], ppB[3], a1);
      a2 = __hfma2(vH[2], ppB[3], a2); a3 = __hfma2(vH[3], ppB[3], a3);
      den += __low2float(ppA[0]) + __low2float(ppA[1]) +
             __low2float(ppA[2]) + __low2float(ppA[3]) +
             __low2float(ppB[0]) + __low2float(ppB[1]) +
             __low2float(ppB[2]) + __low2float(ppB[3]);
    }
    // promote chunk accumulators to fp32
    float2 f0 = __half22float2(a0), f1 = __half22float2(a1);
    float2 f2 = __half22float2(a2), f3 = __half22float2(a3);
    accf[0] += f0.x; accf[1] += f0.y; accf[2] += f1.x; accf[3] += f1.y;
    accf[4] += f2.x; accf[5] += f2.y; accf[6] += f3.x; accf[7] += f3.y;
    asm volatile("s_waitcnt lgkmcnt(0)" ::: "memory");
  }

  // normalize by own head's den, fold in 1/8 head-mean
  float sc = 0.125f / den;
#pragma unroll
  for (int k = 0; k < 8; k++) accf[k] *= sc;
  // sum over heads: xor 2,4,8 within the 16-lane group
#pragma unroll
  for (int off = 2; off <= 8; off <<= 1) {
#pragma unroll
    for (int k = 0; k < 8; k++) accf[k] += __shfl_xor(accf[k], off);
  }
  // lane holds mean for ch (li&1)*8 + k
  int jb = (li & 1) * 8;
  float4 b1a = *(const float4*)(b1 + jb);
  float4 b1b = *(const float4*)(b1 + jb + 4);
  float bv[8] = {b1a.x, b1a.y, b1a.z, b1a.w, b1b.x, b1b.y, b1b.z, b1b.w};
  float r[8];
#pragma unroll
  for (int k = 0; k < 8; k++) {
    float v = accf[k] + bv[k];
    r[k] = v > 0.f ? v : __expf(v) - 1.f;
  }
  float ro[8];
#pragma unroll
  for (int k = 0; k < 8; k++) ro[k] = __shfl_xor(r[k], 1);

  // conv2 transform: outputs j = li, li+16, li+32(li<8)
  float o0 = 0.f, o1 = 0.f, o2 = 0.f;
  bool has2 = li < 8;
#pragma unroll
  for (int k = 0; k < 16; k++) {
    float rk;
    if (k < 8) rk = (li & 1) ? ro[k] : r[k];
    else       rk = (li & 1) ? r[k - 8] : ro[k - 8];
    o0 = fmaf(rk, w2s[k * 40 + li], o0);
    o1 = fmaf(rk, w2s[k * 40 + li + 16], o1);
    if (has2) o2 = fmaf(rk, w2s[k * 40 + li + 32], o2);
  }
  __half* h2r = h2 + d * 40;
  h2r[li] = __float2half(o0);
  h2r[li + 16] = __float2half(o1);
  if (has2) h2r[li + 32] = __float2half(o2);

  float sv = o0 * att_s2[li] + o1 * att_s2[li + 16];
  float dv = o0 * att_d2[li] + o1 * att_d2[li + 16];
  if (has2) {
    sv = fmaf(o2, att_s2[li + 32], sv);
    dv = fmaf(o2, att_d2[li + 32], dv);
  }
#pragma unroll
  for (int off = 1; off <= 8; off <<= 1) {
    sv += __shfl_xor(sv, off);
    dv += __shfl_xor(dv, off);
  }
  if (li == 0) { as2[d] = sv; ad2[d] = dv; }
}

// ---------------- global max of as2 ----------------

__global__ __launch_bounds__(256) void k_maxas2(const float* __restrict__ as2,
                                                unsigned* __restrict__ enc) {
  int t = blockIdx.x * 256 + threadIdx.x;  // 64 blocks -> 16384 threads
  float mx = -1e30f;
  for (int r = t; r < N_NODES; r += 16384) mx = fmaxf(mx, as2[r]);
#pragma unroll
  for (int off = 32; off; off >>= 1) mx = fmaxf(mx, __shfl_xor(mx, off));
  if ((threadIdx.x & 63) == 0) atomicMax(enc, encf(mx));
}

// ---------------- conv2 aggregation + bias + log_softmax ----------------
// 60 lanes = 20 channel-pairs x 3 edge-slots; 2 slot-groups in flight.

__global__ __launch_bounds__(256) void k_agg2(
    const __half* __restrict__ h2, const float* __restrict__ as2,
    const float* __restrict__ ad2, const int* __restrict__ start,
    const int* __restrict__ esrc, const float* __restrict__ b2,
    const unsigned* __restrict__ as2maxEnc, float* __restrict__ out) {
  __shared__ __align__(16) float p_l[4][64];
  __shared__ __align__(16) int s_l[4][64];  // byte offsets (s*80)
  int wave = threadIdx.x >> 6, lane = threadIdx.x & 63;
  int d = blockIdx.x * 4 + wave;
  if (d >= N_NODES) return;
  int s0 = start[d];
  int deg = start[d + 1] - s0;
  float adv = ad2[d];
  float cm = decf(as2maxEnc[0]) + adv;
  cm = cm > 0.f ? cm : 0.2f * cm;

  int cp = lane % 20;        // channel pair (ch 2cp, 2cp+1)
  int es = lane / 20;        // edge slot 0..2 (lanes >= 60 idle in serial)
  const char* h2b = (const char*)h2 + cp * 4;

  float den = 0.f, acc0 = 0.f, acc1 = 0.f;
  for (int be = 0; be < deg; be += 64) {
    int cnt = min(64, deg - be);
    if (lane < cnt) {
      int s = esrc[s0 + be + lane];
      s_l[wave][lane] = s * 80;  // byte offset into h2 (40 halves)
      float e = as2[s] + adv;
      e = e > 0.f ? e : 0.2f * e;
      float p = __expf(e - cm);
      den += p;
      p_l[wave][lane] = p;
    }
    asm volatile("s_waitcnt lgkmcnt(0)" ::: "memory");
    if (es < 3) {
      int i = 0;
      for (; i + 5 < cnt; i += 6) {
        int eA = i + es, eB = i + 3 + es;
        int sbA = s_l[wave][eA], sbB = s_l[wave][eB];
        float pA = p_l[wave][eA], pB = p_l[wave][eB];
        __half2 hvA = *(const __half2*)(h2b + (unsigned)sbA);
        __half2 hvB = *(const __half2*)(h2b + (unsigned)sbB);
        acc0 = fmaf(__half2float(hvA.x), pA, acc0);
        acc1 = fmaf(__half2float(hvA.y), pA, acc1);
        acc0 = fmaf(__half2float(hvB.x), pB, acc0);
        acc1 = fmaf(__half2float(hvB.y), pB, acc1);
      }
      for (; i < cnt; i += 3) {
        int e = i + es;
        if (e < cnt) {
          int sb = s_l[wave][e];
          float p = p_l[wave][e];
          __half2 hv = *(const __half2*)(h2b + (unsigned)sb);
          acc0 = fmaf(__half2float(hv.x), p, acc0);
          acc1 = fmaf(__half2float(hv.y), p, acc1);
        }
      }
    }
    asm volatile("s_waitcnt lgkmcnt(0)" ::: "memory");
  }
#pragma unroll
  for (int off = 32; off; off >>= 1) den += __shfl_xor(den, off);
  float iv = 1.f / den;

  // combine 3 edge-slots: lanes 0..19 gather from +20, +40
  acc0 += __shfl(acc0, lane + 20) + __shfl(acc0, lane + 40);
  acc1 += __shfl(acc1, lane + 20) + __shfl(acc1, lane + 40);
  // distribute pairs to 40-lane layout: channel j from lane j>>1, comp j&1
  float va = __shfl(acc0, lane >> 1);
  float vb = __shfl(acc1, lane >> 1);
  float v = (lane & 1) ? vb : va;
  v = (lane < N_CLS) ? v * iv + b2[lane] : -1e30f;

  float mx = v;
#pragma unroll
  for (int off = 32; off; off >>= 1) mx = fmaxf(mx, __shfl_xor(mx, off));
  float ex = (lane < N_CLS) ? __expf(v - mx) : 0.f;
  float sm = ex;
#pragma unroll
  for (int off = 32; off; off >>= 1) sm += __shfl_xor(sm, off);
  float lse = logf(sm);
  if (lane < N_CLS) out[d * N_CLS + lane] = (v - mx) - lse;
}

// ---------------- host launcher ----------------

extern "C" void kernel_launch(void* const* d_in, const int* in_sizes, int n_in,
                              void* d_out, int out_size, void* d_ws, size_t ws_size,
                              hipStream_t stream) {
  const float* x    = (const float*)d_in[0];
  const int*   ei   = (const int*)d_in[1];
  const float* W1   = (const float*)d_in[2];
  const float* as1w = (const float*)d_in[3];
  const float* ad1w = (const float*)d_in[4];
  const float* b1   = (const float*)d_in[5];
  const float* W2   = (const float*)d_in[6];
  const float* as2w = (const float*)d_in[7];
  const float* ad2w = (const float*)d_in[8];
  const float* b2   = (const float*)d_in[9];
  float* out = (float*)d_out;

  char* ws = (char*)d_ws;
  size_t off = 0;
  auto alloc = [&](size_t bytes) -> void* {
    void* p = ws + off;
    off += (bytes + 255) & ~(size_t)255;
    return p;
  };
  __half* h1   = (__half*)alloc((size_t)N_NODES * 128 * 2);
  float* as1   = (float*)alloc((size_t)N_NODES * 8 * 4);
  float* ad1   = (float*)alloc((size_t)N_NODES * 8 * 4);
  __half* h2   = (__half*)alloc((size_t)N_NODES * 40 * 2);
  float* as2   = (float*)alloc((size_t)N_NODES * 4);
  float* ad2   = (float*)alloc((size_t)N_NODES * 4);
  // contiguous zero region: deg | maxenc(16)
  size_t zbytes = (size_t)N_NODES * 4 + 256;
  int* deg     = (int*)alloc(zbytes);
  unsigned* maxenc = (unsigned*)(deg + N_NODES);  // [0..7]=as1 heads, [8]=as2
  int* start   = (int*)alloc((size_t)(N_NODES + 1) * 4);
  int* esrc    = (int*)alloc((size_t)ET * 4);
  int* epos    = (int*)alloc((size_t)ET * 4);
  int* bsum    = (int*)alloc((size_t)NSCB * 4);
  int* boff    = (int*)alloc(256 * 4);
  float* fmax1 = (float*)alloc(32);

  (void)hipMemsetAsync(deg, 0, zbytes, stream);

  k_xform1<<<XB + HB, 256, 0, stream>>>(x, W1, as1w, ad1w, ei, deg, epos,
                                        h1, as1, ad1, maxenc);
  k_scanA<<<NSCB, 256, 0, stream>>>(deg, bsum);
  k_scanB<<<1, 256, 0, stream>>>(bsum, boff, start, maxenc, fmax1);
  k_scanC<<<NSCB, 256, 0, stream>>>(deg, boff, start);
  k_scatter<<<HB, 256, 0, stream>>>(ei, start, epos, esrc);

  k_agg1<<<N_NODES / 16, 256, 0, stream>>>(h1, as1, ad1, start, esrc, b1,
                                           W2, as2w, ad2w, fmax1,
                                           h2, as2, ad2);
  k_maxas2<<<64, 256, 0, stream>>>(as2, maxenc + 8);
  k_agg2<<<(N_NODES + 3) / 4, 256, 0, stream>>>(h2, as2, ad2, start, esrc, b2,
                                                maxenc + 8, out);
}